// Round 11
// baseline (241.247 us; speedup 1.0000x reference)
//
#include <hip/hip_runtime.h>

typedef __bf16 bf16_t;
typedef __bf16 bf16x8 __attribute__((ext_vector_type(8)));
typedef float f32x4 __attribute__((ext_vector_type(4)));
typedef unsigned short u16;
typedef unsigned short u16x4 __attribute__((ext_vector_type(4)));
typedef unsigned int u32;

#define B_ 4
#define N_ 64
#define P_ 256
#define C_ 384
#define H_ 6
#define D_ 64
#define M_TOTAL 65536
#define NQKV 1152
#define KSTEPS 12                     // 384/32
#define NBLK (H_*B_*N_)               // 1536 = 8 XCDs * 192
#define WKS_U16 10240                 // 20KB per (h,ks): 12 hi frags + 8 lo frags x 1KB
#define WKS_BYTES 20480
#define FUSED_LDS 131072
#define PB_STRIDE 40
#define PROJ_LDS 65536
#define SB() __builtin_amdgcn_sched_barrier(0)

#define GLOAD_LDS16(g, l) __builtin_amdgcn_global_load_lds( \
    (const __attribute__((address_space(1))) void*)(g), \
    (__attribute__((address_space(3))) void*)(l), 16, 0, 0)
#define GLOAD_LDS4(g, l) __builtin_amdgcn_global_load_lds( \
    (const __attribute__((address_space(1))) void*)(g), \
    (__attribute__((address_space(3))) void*)(l), 4, 0, 0)

__device__ __forceinline__ u16 f2b(float f){ return __builtin_bit_cast(u16, (bf16_t)f); }
__device__ __forceinline__ f32x4 mfma(bf16x8 a, bf16x8 b, f32x4 c){
    return __builtin_amdgcn_mfma_f32_16x16x32_bf16(a, b, c, 0, 0, 0);
}

// ---------------------------------------------------------------------------
// prep_attn: one block per (h,ks). Coalesced read of the 32x192 wqkv slice
// into LDS, then split+pack into Wpk fragments with coalesced writes.
// Layout (unchanged): Wpk[(h*12+ks)*10240 + nf*512 + lane*8 + e] (hi, nf<12)
//                     ... + 6144 + nf*512 + lane*8 + e          (lo, nf<8)
// ---------------------------------------------------------------------------
__global__ __launch_bounds__(256) void prep_attn(
    const float* __restrict__ wqkv, u16* __restrict__ Wpk)
{
    __shared__ float tile[32][192];
    const int h  = blockIdx.x / KSTEPS;
    const int ks = blockIdx.x % KSTEPS;
    const int tid = threadIdx.x;

    // coalesced load: 6144 f32, 24 per thread
    #pragma unroll
    for (int it = 0; it < 24; ++it) {
        int idx = tid + 256 * it;
        int row = idx / 192, cc = idx % 192;
        int part = cc / 64, c = cc % 64;
        tile[row][cc] = wqkv[(size_t)(ks * 32 + row) * NQKV + part * C_ + h * 64 + c];
    }
    __syncthreads();

    const size_t base = (size_t)(h * KSTEPS + ks) * WKS_U16;
    #pragma unroll
    for (int it = 0; it < 3; ++it) {
        int slot = tid + 256 * it;          // 768 slots = 12 frags x 64 lanes
        int nf = slot >> 6, lane = slot & 63;
        int r16 = lane & 15, g = lane >> 4;
        int part = nf >> 2;
        int cc = part * 64 + (nf & 3) * 16 + r16;
        #pragma unroll
        for (int e = 0; e < 8; ++e) {
            float w = tile[g * 8 + e][cc];
            bf16_t hi = (bf16_t)w;
            Wpk[base + nf * 512 + lane * 8 + e] = __builtin_bit_cast(u16, hi);
            if (nf < 8)
                Wpk[base + 6144 + nf * 512 + lane * 8 + e] = f2b(w - (float)hi);
        }
    }
}

// ---------------------------------------------------------------------------
// prep_proj: one block per ks. Coalesced read of wproj rows ks*32..+32 into
// LDS, pack as B-fragments: wPj[ks*12288 + nf*512 + lane*8 + e]
//   = bf16(wproj[k = ks*32+8g+e][n = nf*16+r16]),  nf in [0,24).
// ---------------------------------------------------------------------------
__global__ __launch_bounds__(256) void prep_proj(
    const float* __restrict__ wproj, u16* __restrict__ wPj)
{
    __shared__ float tile[32][384];
    const int ks = blockIdx.x;
    const int tid = threadIdx.x;

    #pragma unroll
    for (int it = 0; it < 48; ++it) {
        int idx = tid + 256 * it;           // 12288 f32
        int row = idx / 384, n = idx % 384;
        tile[row][n] = wproj[(size_t)(ks * 32 + row) * C_ + n];
    }
    __syncthreads();

    const size_t base = (size_t)ks * 12288;
    #pragma unroll
    for (int it = 0; it < 6; ++it) {
        int slot = tid + 256 * it;          // 1536 slots = 24 frags x 64 lanes
        int nf = slot >> 6, lane = slot & 63;
        int r16 = lane & 15, g = lane >> 4;
        int n = nf * 16 + r16;
        #pragma unroll
        for (int e = 0; e < 8; ++e)
            wPj[base + nf * 512 + lane * 8 + e] = f2b(tile[g * 8 + e][n]);
    }
}

// ---------------------------------------------------------------------------
// fused per-(h, b*n) kernel — UNCHANGED from round 10 (best known).
// ---------------------------------------------------------------------------
__global__ __launch_bounds__(1024, 4) void fused_attn(
    const float* __restrict__ x, const u16* __restrict__ Wpk,
    u16* __restrict__ attn)
{
    extern __shared__ u16 sm[];
    u16* Kh = sm;              // valid from epilogue (stage bufs live here ph1)
    u16* Kl = sm + 16384;
    u16* Vt = sm + 32768;

    const int tid  = threadIdx.x;
    const int lane = tid & 63, wid = tid >> 6;
    const int g = lane >> 4, r16 = lane & 15;

    // XCD-chunk swizzle (bijective: 1536 = 8 * 192)
    const int p = blockIdx.x;
    const int logical = (p & 7) * (NBLK / 8) + (p >> 3);
    const int h  = logical % H_;
    const int bn = logical / H_;
    const size_t row0 = (size_t)bn * P_;
    const int m0w = wid * 16;

    // ---------------- phase 1: [Q|K|V](16 rows) = X @ W3head, split bf16 ---
    f32x4 acc[12];
    #pragma unroll
    for (int nf = 0; nf < 12; ++nf) acc[nf] = f32x4{0.f,0.f,0.f,0.f};

    const float* xr0 = x + (row0 + m0w + r16) * C_;
    const char* wbase = (const char*)Wpk + (size_t)h * (KSTEPS * WKS_BYTES);

#define STAGE(ks_, b_) do { \
    const char* _gp = wbase + (size_t)(ks_) * WKS_BYTES; \
    char* _lp = (char*)(sm + (b_) * WKS_U16); \
    GLOAD_LDS16(_gp + tid * 16, _lp + tid * 16); \
    GLOAD_LDS4(_gp + 16384 + tid * 4, _lp + 16384 + tid * 4); \
} while (0)

    f32x4 xr[2][2];
#define XLOAD(ks_, par_) do { \
    const float* _xp = xr0 + (ks_) * 32 + 8 * g; \
    xr[par_][0] = *(const f32x4*)_xp; xr[par_][1] = *(const f32x4*)(_xp + 4); \
} while (0)

    bf16x8 ah, al;
#define SPLIT_A(par_) do { \
    _Pragma("unroll") \
    for (int e = 0; e < 4; ++e) { \
        bf16_t h0 = (bf16_t)xr[par_][0][e], h1 = (bf16_t)xr[par_][1][e]; \
        ah[e]   = h0; al[e]   = (bf16_t)(xr[par_][0][e] - (float)h0); \
        ah[4+e] = h1; al[4+e] = (bf16_t)(xr[par_][1][e] - (float)h1); \
    } } while (0)

    STAGE(0, 0);
    XLOAD(0, 0);
    STAGE(1, 1);
    SB();
    asm volatile("s_waitcnt vmcnt(2)" ::: "memory");
    __builtin_amdgcn_s_barrier();
    SB();

    #pragma unroll
    for (int ks = 0; ks < KSTEPS; ++ks) {
        const int par = ks & 1, nxt = par ^ 1;
        if (ks + 2 < KSTEPS) STAGE(ks + 2, (ks + 2) % 3);
        if (ks + 1 < KSTEPS) XLOAD(ks + 1, nxt);
        SPLIT_A(par);

        const u16* stg = sm + (ks % 3) * WKS_U16;
        #pragma unroll
        for (int nf = 0; nf < 8; ++nf) {    // Q,K: split 3x
            bf16x8 bh = *(const bf16x8*)&stg[nf * 512 + lane * 8];
            bf16x8 bl = *(const bf16x8*)&stg[6144 + nf * 512 + lane * 8];
            acc[nf] = mfma(ah, bh, acc[nf]);
            acc[nf] = mfma(ah, bl, acc[nf]);
            acc[nf] = mfma(al, bh, acc[nf]);
        }
        #pragma unroll
        for (int nf = 8; nf < 12; ++nf) {   // V: plain
            bf16x8 bh = *(const bf16x8*)&stg[nf * 512 + lane * 8];
            acc[nf] = mfma(ah, bh, acc[nf]);
        }

        if (ks < KSTEPS - 1) {
            SB();
            if (ks + 2 < KSTEPS) asm volatile("s_waitcnt vmcnt(4)" ::: "memory");
            else                 asm volatile("s_waitcnt vmcnt(2)" ::: "memory");
            __builtin_amdgcn_s_barrier();
            SB();
        } else {
            __syncthreads();
        }
    }

    // ---- epilogue: K -> Kh/Kl (split), V -> Vt (b64-packed), swizzled ----
    #pragma unroll
    for (int f = 0; f < 4; ++f) {
        const int d = f * 16 + r16;
        const int q0 = m0w + 4 * g;
        u16x4 vv;
        #pragma unroll
        for (int rr = 0; rr < 4; ++rr) vv[rr] = f2b(acc[8 + f][rr]);
        *(u16x4*)&Vt[d * 256 + (((q0 >> 3) ^ (d & 7)) << 3) + (q0 & 7)] = vv;
        #pragma unroll
        for (int rr = 0; rr < 4; ++rr) {
            int q = q0 + rr;
            int ek = q * 64 + (((d >> 3) ^ (q & 7)) << 3) + (d & 7);
            float kv = acc[4 + f][rr];
            bf16_t khi = (bf16_t)kv;
            Kh[ek] = __builtin_bit_cast(u16, khi);
            Kl[ek] = f2b(kv - (float)khi);
        }
    }

    // ---- Q bounce (per-wave region, two passes hi/lo) ----
    u16* myQb = sm + 49152 + wid * 1024;   // [16][64] swizzled
    bf16x8 aqh[2], aql[2];
    #pragma unroll
    for (int f = 0; f < 4; ++f)
    #pragma unroll
    for (int rr = 0; rr < 4; ++rr) {
        int r = 4 * g + rr;
        int c = f * 16 + r16;
        myQb[r * 64 + (((c >> 3) ^ (r & 7)) << 3) + (c & 7)] = f2b(acc[f][rr]);
    }
    #pragma unroll
    for (int k2 = 0; k2 < 2; ++k2)
        aqh[k2] = *(const bf16x8*)&myQb[r16 * 64 + (((k2 * 4 + g) ^ (r16 & 7)) << 3)];
    SB();
    #pragma unroll
    for (int f = 0; f < 4; ++f)
    #pragma unroll
    for (int rr = 0; rr < 4; ++rr) {
        int r = 4 * g + rr;
        int c = f * 16 + r16;
        float v = acc[f][rr];
        bf16_t hi = (bf16_t)v;
        myQb[r * 64 + (((c >> 3) ^ (r & 7)) << 3) + (c & 7)] = f2b(v - (float)hi);
    }
    #pragma unroll
    for (int k2 = 0; k2 < 2; ++k2)
        aql[k2] = *(const bf16x8*)&myQb[r16 * 64 + (((k2 * 4 + g) ^ (r16 & 7)) << 3)];

    __syncthreads();   // Kh/Kl/Vt visible block-wide

    // ---------------- phase 2: S^T = K Q^T (swapped operands, split 3x) ----
    f32x4 S[16];
    #pragma unroll
    for (int nf = 0; nf < 16; ++nf) S[nf] = f32x4{0.f,0.f,0.f,0.f};

    const int kb0 = r16 * 64 + (((0 * 4 + g) ^ (r16 & 7)) << 3);
    const int kb1 = r16 * 64 + (((1 * 4 + g) ^ (r16 & 7)) << 3);

    bf16x8 khv[2][2], klv[2][2];
    {
        khv[0][0] = *(const bf16x8*)&Kh[kb0];
        klv[0][0] = *(const bf16x8*)&Kl[kb0];
        khv[0][1] = *(const bf16x8*)&Kh[kb1];
        klv[0][1] = *(const bf16x8*)&Kl[kb1];
    }
    #pragma unroll
    for (int nf = 0; nf < 16; ++nf) {
        const int par = nf & 1, nxt = par ^ 1;
        if (nf < 15) {
            const int o = (nf + 1) * 1024;
            khv[nxt][0] = *(const bf16x8*)&Kh[o + kb0];
            klv[nxt][0] = *(const bf16x8*)&Kl[o + kb0];
            khv[nxt][1] = *(const bf16x8*)&Kh[o + kb1];
            klv[nxt][1] = *(const bf16x8*)&Kl[o + kb1];
        }
        SB();
        __builtin_amdgcn_s_setprio(1);
        #pragma unroll
        for (int k2 = 0; k2 < 2; ++k2) {
            S[nf] = mfma(khv[par][k2], aqh[k2], S[nf]);
            S[nf] = mfma(klv[par][k2], aqh[k2], S[nf]);
            S[nf] = mfma(khv[par][k2], aql[k2], S[nf]);
        }
        __builtin_amdgcn_s_setprio(0);
        SB();
    }

    // ---------------- softmax: each lane owns one q-row's 64 samples -------
    float inv_;
    {
        float m = -1e30f;
        #pragma unroll
        for (int nf = 0; nf < 16; ++nf)
            #pragma unroll
            for (int rr = 0; rr < 4; ++rr) m = fmaxf(m, S[nf][rr]);
        m = fmaxf(m, __shfl_xor(m, 16, 64));
        m = fmaxf(m, __shfl_xor(m, 32, 64));
        float s = 0.f;
        #pragma unroll
        for (int nf = 0; nf < 16; ++nf)
            #pragma unroll
            for (int rr = 0; rr < 4; ++rr) {
                float pv = __expf((S[nf][rr] - m) * 64.0f);  // scale = D
                S[nf][rr] = pv;
                s += pv;
            }
        s += __shfl_xor(s, 16, 64);
        s += __shfl_xor(s, 32, 64);
        inv_ = 1.0f / s;
    }

    // ---------------- phase 3: O = P V (packed b64 P-bounce) ---------------
    f32x4 O[4];
    #pragma unroll
    for (int f = 0; f < 4; ++f) O[f] = f32x4{0.f,0.f,0.f,0.f};

    u16* pt = sm + 49152 + wid * 1024;
    const int vc = r16 & 7;
    #pragma unroll
    for (int t = 0; t < 8; ++t) {
        bf16x8 bv[4];
        const int vo = (((4 * t + g) ^ vc) << 3) + r16 * 256;
        #pragma unroll
        for (int f = 0; f < 4; ++f)
            bv[f] = *(const bf16x8*)&Vt[f * 4096 + vo];
        #pragma unroll
        for (int nu = 0; nu < 2; ++nu) {
            int nf = 2 * t + nu;
            u16x4 pk;
            #pragma unroll
            for (int rr = 0; rr < 4; ++rr) pk[rr] = f2b(S[nf][rr] * inv_);
            *(u16x4*)&pt[r16 * PB_STRIDE + nu * 16 + 4 * g] = pk;
        }
        bf16x8 ap = *(const bf16x8*)&pt[r16 * PB_STRIDE + 8 * g];
        __builtin_amdgcn_s_setprio(1);
        #pragma unroll
        for (int f = 0; f < 4; ++f) O[f] = mfma(ap, bv[f], O[f]);
        __builtin_amdgcn_s_setprio(0);
    }

    #pragma unroll
    for (int f = 0; f < 4; ++f)
    #pragma unroll
    for (int rr = 0; rr < 4; ++rr)
        attn[(row0 + m0w + 4 * g + rr) * C_ + h * 64 + f * 16 + r16] = f2b(O[f][rr]);
}

// ---------------------------------------------------------------------------
// proj v2: 128x384 full-N tiles -> attnb read ONCE (HBM 250->150 MB).
// 512 threads = 8 waves (4 row-groups x 2 col-groups); A+B staged via
// global_load_lds double-buffer; B pre-packed in fragment order (wPj).
// ---------------------------------------------------------------------------
__global__ __launch_bounds__(512, 2) void proj_kernel(
    const u16* __restrict__ attn, const u16* __restrict__ wPj,
    const float* __restrict__ bias, float* __restrict__ out)
{
    extern __shared__ u16 psm[];
    // layout (u16): Ast[2] @ 0 / 4096 (128x32 each), Bst[2] @ 8192 / 20480 (12288 each)
    const int tid = threadIdx.x;
    const int lane = tid & 63, wid = tid >> 6;
    const int rw = wid >> 1, cw = wid & 1;
    const int g = lane >> 4, r16 = lane & 15;
    const size_t m0 = (size_t)blockIdx.x * 128;

#define PSTAGE(ks_, b_) do { \
    const u16* _as = attn + (m0 + (tid >> 2)) * C_ + (ks_) * 32 + (tid & 3) * 8; \
    GLOAD_LDS16(_as, (char*)(psm + (b_) * 4096) + tid * 16); \
    const u16* _bs = wPj + (size_t)(ks_) * 12288; \
    char* _bl = (char*)(psm + 8192 + (b_) * 12288); \
    GLOAD_LDS16(_bs + tid * 8,            _bl + tid * 16); \
    GLOAD_LDS16(_bs + 4096 + tid * 8,     _bl + 8192 + tid * 16); \
    GLOAD_LDS16(_bs + 8192 + tid * 8,     _bl + 16384 + tid * 16); \
} while (0)

    f32x4 acc[2][12];
    #pragma unroll
    for (int mf = 0; mf < 2; ++mf)
        #pragma unroll
        for (int nf = 0; nf < 12; ++nf) acc[mf][nf] = f32x4{0.f,0.f,0.f,0.f};

    PSTAGE(0, 0);
    __syncthreads();

    for (int ks = 0; ks < KSTEPS; ++ks) {
        const int cur = ks & 1, nxt = cur ^ 1;
        if (ks + 1 < KSTEPS) PSTAGE(ks + 1, nxt);

        const u16* Ab = psm + cur * 4096;
        const u16* Bb = psm + 8192 + cur * 12288;
        bf16x8 a[2];
        #pragma unroll
        for (int mf = 0; mf < 2; ++mf)
            a[mf] = *(const bf16x8*)&Ab[(rw * 32 + mf * 16 + r16) * 32 + 8 * g];
        #pragma unroll
        for (int nf = 0; nf < 12; ++nf) {
            bf16x8 b = *(const bf16x8*)&Bb[(cw * 12 + nf) * 512 + lane * 8];
            acc[0][nf] = mfma(a[0], b, acc[0][nf]);
            acc[1][nf] = mfma(a[1], b, acc[1][nf]);
        }
        __syncthreads();
    }

    #pragma unroll
    for (int mf = 0; mf < 2; ++mf)
    #pragma unroll
    for (int nf = 0; nf < 12; ++nf) {
        int col = cw * 192 + nf * 16 + r16;
        float bb = bias[col];
        #pragma unroll
        for (int rr = 0; rr < 4; ++rr) {
            size_t row = m0 + rw * 32 + mf * 16 + 4 * g + rr;
            out[row * C_ + col] = acc[mf][nf][rr] + bb;
        }
    }
}

// ---------------------------------------------------------------------------
extern "C" void kernel_launch(void* const* d_in, const int* in_sizes, int n_in,
                              void* d_out, int out_size, void* d_ws, size_t ws_size,
                              hipStream_t stream)
{
    const float* x      = (const float*)d_in[0];
    const float* w_qkv  = (const float*)d_in[1];
    const float* w_proj = (const float*)d_in[2];
    const float* b_proj = (const float*)d_in[3];
    float* out = (float*)d_out;

    u16* ws = (u16*)d_ws;
    u16* attnb = ws;                                  // 65536*384 u16 = 50 MB
    size_t off = (size_t)M_TOTAL * C_;
    u16* Wpk = ws + off; off += (size_t)H_ * KSTEPS * WKS_U16;
    u16* wPj = ws + off; off += (size_t)KSTEPS * 12288;

    hipFuncSetAttribute((const void*)fused_attn,
                        hipFuncAttributeMaxDynamicSharedMemorySize, FUSED_LDS);
    hipFuncSetAttribute((const void*)proj_kernel,
                        hipFuncAttributeMaxDynamicSharedMemorySize, PROJ_LDS);

    prep_attn<<<dim3(H_ * KSTEPS), 256, 0, stream>>>(w_qkv, Wpk);
    prep_proj<<<dim3(KSTEPS), 256, 0, stream>>>(w_proj, wPj);
    fused_attn<<<dim3(NBLK), 1024, FUSED_LDS, stream>>>(x, Wpk, attnb);
    proj_kernel<<<dim3(M_TOTAL / 128), 512, PROJ_LDS, stream>>>(attnb, wPj, b_proj, out);
}